// Round 1
// baseline (1114.202 us; speedup 1.0000x reference)
//
#include <hip/hip_runtime.h>
#include <math.h>

// Problem constants (fixed by setup_inputs)
constexpr int C_  = 1024;
constexpr int H_  = 128;
constexpr int W_  = 128;
constexpr int HW_ = H_ * W_;
constexpr int N_  = 8192;
constexpr int NCOMP = 28;      // cost, g[6], H upper-tri[21]
constexpr int ITERS = 10;

// state layout (floats):
//  0-8   R (row-major)
//  9-11  t
//  12    lam
//  13    prev
//  14-22 R_new
//  23-25 t_new
//  26-31 delta
//  32-40 K1
//  41 fx  42 fy  43 size_ratio (as float)
//  44-71 reduced sums: cost, g[6], H[21]
//  72    nan flag for delta

// ---------------------------------------------------------------- init pose
__global__ void k_init(const float* __restrict__ q, const float* __restrict__ r,
                       const float* __restrict__ K1, const int* __restrict__ srp,
                       float* __restrict__ st) {
    if (threadIdx.x != 0 || blockIdx.x != 0) return;
    // invert r_matrix (4x4) via Gauss-Jordan in double
    double a[4][8];
    for (int i = 0; i < 4; i++)
        for (int j = 0; j < 4; j++) { a[i][j] = r[i*4+j]; a[i][j+4] = (i == j) ? 1.0 : 0.0; }
    for (int col = 0; col < 4; col++) {
        int piv = col; double mx = fabs(a[col][col]);
        for (int i = col+1; i < 4; i++) if (fabs(a[i][col]) > mx) { mx = fabs(a[i][col]); piv = i; }
        if (piv != col) for (int j = 0; j < 8; j++) { double t = a[col][j]; a[col][j] = a[piv][j]; a[piv][j] = t; }
        double d = a[col][col];
        for (int j = 0; j < 8; j++) a[col][j] /= d;
        for (int i = 0; i < 4; i++) if (i != col) {
            double f = a[i][col];
            for (int j = 0; j < 8; j++) a[i][j] -= f * a[col][j];
        }
    }
    double rel[4][4];
    for (int i = 0; i < 4; i++)
        for (int j = 0; j < 4; j++) {
            double s = 0;
            for (int k = 0; k < 4; k++) s += (double)q[i*4+k] * a[k][j+4];
            rel[i][j] = s;
        }
    for (int i = 0; i < 3; i++)
        for (int j = 0; j < 3; j++) st[i*3+j] = (float)rel[i][j];
    st[9]  = (float)rel[3][0];
    st[10] = (float)rel[3][1];
    st[11] = (float)rel[3][2];
    st[12] = 0.01f;                 // LAMBDA0
    st[13] = __builtin_inff();      // prev
    for (int i = 0; i < 9; i++) st[32+i] = K1[i];
    st[41] = K1[0]; st[42] = K1[4];
    st[43] = (float)srp[0];
}

// ------------------------------------------------------- pts0 + pix0 (once)
__global__ void k_pts0(const float* __restrict__ p3d, const float* __restrict__ p2d,
                       const float* __restrict__ r, const int* __restrict__ srp,
                       float* __restrict__ pts0, int* __restrict__ pix0) {
    int n = blockIdx.x * blockDim.x + threadIdx.x;
    if (n >= N_) return;
    float sr = (float)srp[0];
    float ph[4] = { p3d[n*3+0], p3d[n*3+1], p3d[n*3+2], 1.f };
    float h[4];
    for (int i = 0; i < 4; i++) {
        float s = 0.f;
        for (int j = 0; j < 4; j++) s += r[i*4+j] * ph[j];
        h[i] = s;
    }
    pts0[n*3+0] = h[0]/h[3];
    pts0[n*3+1] = h[1]/h[3];
    pts0[n*3+2] = h[2]/h[3];
    int ix = (int)floorf(p2d[n*2+0] / sr); ix = min(max(ix, 0), W_-1);
    int iy = (int)floorf(p2d[n*2+1] / sr); iy = min(max(iy, 0), H_-1);
    pix0[n] = iy * W_ + ix;
}

// -------------------------------- transpose (C,H,W)->(HW,C), optional sobel
template <bool SOBEL>
__global__ void k_transpose(const float* __restrict__ src, float* __restrict__ dq,
                            float* __restrict__ dgx, float* __restrict__ dgy) {
    __shared__ float tile[64][3][66];
    const int x0 = blockIdx.x * 64;
    const int y  = blockIdx.y;
    const int cc = blockIdx.z * 64;
    const int tid = threadIdx.x;
    for (int idx = tid; idx < 64*3*66; idx += 256) {
        int c   = idx / 198;
        int rem = idx % 198;
        int rr  = rem / 66;
        int xx  = rem % 66;
        int gy_ = y + rr - 1;
        int gx_ = x0 - 1 + xx;
        float v = 0.f;
        if (gy_ >= 0 && gy_ < H_ && gx_ >= 0 && gx_ < W_)
            v = src[(size_t)(cc + c) * HW_ + gy_ * W_ + gx_];
        tile[c][rr][xx] = v;
    }
    __syncthreads();
    const int c  = tid & 63;
    const int pb = tid >> 6;
    for (int p = 0; p < 16; p++) {
        int px = p * 4 + pb;
        size_t o = ((size_t)(y * W_ + x0 + px)) * C_ + cc + c;
        dq[o] = tile[c][1][px+1];
        if (SOBEL) {
            float t0l = tile[c][0][px], t0m = tile[c][0][px+1], t0r = tile[c][0][px+2];
            float t1l = tile[c][1][px],                          t1r = tile[c][1][px+2];
            float t2l = tile[c][2][px], t2m = tile[c][2][px+1], t2r = tile[c][2][px+2];
            dgx[o] = (t0r - t0l) + 2.f*(t1r - t1l) + (t2r - t2l);
            dgy[o] = (t2l + 2.f*t2m + t2r) - (t0l + 2.f*t0m + t0r);
        }
    }
}

// ---------------------------------------------------- feat0 gather (coalesced)
__global__ void k_feat0(const float* __restrict__ rT, const int* __restrict__ pix0,
                        float* __restrict__ feat0) {
    int n = blockIdx.x;
    const float4* s = (const float4*)(rT + (size_t)pix0[n] * C_);
    float4* d = (float4*)(feat0 + (size_t)n * C_);
    d[threadIdx.x] = s[threadIdx.x];
}

__device__ inline float waveSum(float v) {
    for (int o = 32; o; o >>= 1) v += __shfl_down(v, o, 64);
    return v;
}

// ------------------------------------------------------------------- pass A
__global__ void k_passA(const float* __restrict__ qT, const float* __restrict__ gxT,
                        const float* __restrict__ gyT, const float* __restrict__ feat0,
                        const float* __restrict__ pts0, const float* __restrict__ st,
                        float* __restrict__ parts) {
    const int n = blockIdx.x;
    const int tid = threadIdx.x;
    const float p0 = pts0[n*3+0], p1 = pts0[n*3+1], p2 = pts0[n*3+2];
    // pts1 = pts0 @ R + t
    const float X = p0*st[0] + p1*st[3] + p2*st[6] + st[9];
    const float Y = p0*st[1] + p1*st[4] + p2*st[7] + st[10];
    const float Z = p0*st[2] + p1*st[5] + p2*st[8] + st[11];
    const float hx = st[32]*X + st[33]*Y + st[34]*Z;
    const float hy = st[35]*X + st[36]*Y + st[37]*Z;
    const float hz = st[38]*X + st[39]*Y + st[40]*Z;
    const float sr = st[43];
    const float u = hx / hz, v = hy / hz;
    int ix = (int)floorf(u / sr); ix = min(max(ix, 0), W_-1);
    int iy = (int)floorf(v / sr); iy = min(max(iy, 0), H_-1);
    const int pix = iy * W_ + ix;

    const float4* q4 = (const float4*)(qT  + (size_t)pix * C_);
    const float4* g4 = (const float4*)(gxT + (size_t)pix * C_);
    const float4* h4 = (const float4*)(gyT + (size_t)pix * C_);
    const float4* f4 = (const float4*)(feat0 + (size_t)n * C_);
    float4 qv = q4[tid], gv = g4[tid], yv = h4[tid], fv = f4[tid];

    float cost = 0, bx = 0, by = 0, mxx = 0, mxy = 0, myy = 0;
    {
        float e;
        e = qv.x - fv.x; cost += e*e; bx += gv.x*e; by += yv.x*e; mxx += gv.x*gv.x; mxy += gv.x*yv.x; myy += yv.x*yv.x;
        e = qv.y - fv.y; cost += e*e; bx += gv.y*e; by += yv.y*e; mxx += gv.y*gv.y; mxy += gv.y*yv.y; myy += yv.y*yv.y;
        e = qv.z - fv.z; cost += e*e; bx += gv.z*e; by += yv.z*e; mxx += gv.z*gv.z; mxy += gv.z*yv.z; myy += yv.z*yv.z;
        e = qv.w - fv.w; cost += e*e; bx += gv.w*e; by += yv.w*e; mxx += gv.w*gv.w; mxy += gv.w*yv.w; myy += yv.w*yv.w;
    }
    cost = waveSum(cost); bx = waveSum(bx); by = waveSum(by);
    mxx = waveSum(mxx); mxy = waveSum(mxy); myy = waveSum(myy);

    __shared__ float red[4][6];
    int wid = tid >> 6, lane = tid & 63;
    if (lane == 0) {
        red[wid][0] = cost; red[wid][1] = bx;  red[wid][2] = by;
        red[wid][3] = mxx;  red[wid][4] = mxy; red[wid][5] = myy;
    }
    __syncthreads();
    if (tid == 0) {
        cost = red[0][0]+red[1][0]+red[2][0]+red[3][0];
        bx   = red[0][1]+red[1][1]+red[2][1]+red[3][1];
        by   = red[0][2]+red[1][2]+red[2][2]+red[3][2];
        mxx  = red[0][3]+red[1][3]+red[2][3]+red[3][3];
        mxy  = red[0][4]+red[1][4]+red[2][4]+red[3][4];
        myy  = red[0][5]+red[1][5]+red[2][5]+red[3][5];

        const float fx = st[41], fy = st[42];
        const float s = 1.f / (Z * sr);
        const float jh00 = fx, jh02 = -fx * X / Z;
        const float jh11 = fy, jh12 = -fy * Y / Z;
        // J_p_T rows: [1,0,0,0,Z,-Y], [0,1,0,-Z,0,X], [0,0,1,Y,-X,0]
        float A0[6], A1[6];
        A0[0] = s*jh00; A0[1] = 0.f;    A0[2] = s*jh02;
        A0[3] = s*(jh02*Y); A0[4] = s*(jh00*Z - jh02*X); A0[5] = s*(-jh00*Y);
        A1[0] = 0.f;    A1[1] = s*jh11; A1[2] = s*jh12;
        A1[3] = s*(-jh11*Z + jh12*Y); A1[4] = s*(-jh12*X); A1[5] = s*(jh11*X);

        parts[0*N_ + n] = cost;
        for (int k = 0; k < 6; k++) parts[(1+k)*N_ + n] = A0[k]*bx + A1[k]*by;
        int idx = 7;
        for (int k = 0; k < 6; k++)
            for (int l = k; l < 6; l++) {
                parts[idx*N_ + n] = A0[k]*A0[l]*mxx + (A0[k]*A1[l] + A1[k]*A0[l])*mxy + A1[k]*A1[l]*myy;
                idx++;
            }
    }
}

// -------------------------------------------------- deterministic reduction
__global__ void k_reduce(const float* __restrict__ parts, float* __restrict__ st) {
    const int comp = blockIdx.x;
    const int tid = threadIdx.x;
    double s = 0;
    for (int i = tid; i < N_; i += 256) s += (double)parts[comp*N_ + i];
    __shared__ double sd[256];
    sd[tid] = s;
    __syncthreads();
    for (int k = 128; k; k >>= 1) { if (tid < k) sd[tid] += sd[tid+k]; __syncthreads(); }
    if (tid == 0) st[44 + comp] = (float)sd[0];
}

// ------------------------------------------------------- LM solve + update
__global__ void k_solve(float* __restrict__ st, int iter) {
    if (threadIdx.x != 0 || blockIdx.x != 0) return;
    double costsum = st[44];
    if (iter == 0) st[13] = (float)(costsum / (double)N_);
    double g[6];
    for (int k = 0; k < 6; k++) g[k] = st[45+k];
    double Hs[6][6];
    int idx = 51;
    for (int k = 0; k < 6; k++)
        for (int l = k; l < 6; l++) { Hs[k][l] = st[idx]; Hs[l][k] = st[idx]; idx++; }
    double lam = st[12];
    double M[6][7];
    for (int i = 0; i < 6; i++) {
        for (int j = 0; j < 6; j++) M[i][j] = Hs[i][j];
        M[i][i] += (Hs[i][i] + 1e-9) * lam;
        M[i][6] = -g[i];
    }
    for (int col = 0; col < 6; col++) {
        int piv = col; double mx = fabs(M[col][col]);
        for (int i = col+1; i < 6; i++) if (fabs(M[i][col]) > mx) { mx = fabs(M[i][col]); piv = i; }
        if (piv != col) for (int j = col; j < 7; j++) { double t = M[col][j]; M[col][j] = M[piv][j]; M[piv][j] = t; }
        double d = M[col][col];
        for (int j = col; j < 7; j++) M[col][j] /= d;
        for (int i = 0; i < 6; i++) if (i != col) {
            double f = M[i][col];
            if (f != 0.0) for (int j = col; j < 7; j++) M[i][j] -= f * M[col][j];
        }
    }
    double delta[6];
    int bad = 0;
    for (int i = 0; i < 6; i++) {
        delta[i] = M[i][6];
        st[26+i] = (float)delta[i];
        if (isnan(st[26+i])) bad = 1;
    }
    st[72] = (float)bad;
    double w0 = delta[3], w1 = delta[4], w2 = delta[5];
    double th2 = w0*w0 + w1*w1 + w2*w2 + 1e-12;
    double th = sqrt(th2);
    double Af = sin(th) / th, Bf = (1.0 - cos(th)) / th2;
    double Wm[3][3] = {{0,-w2,w1},{w2,0,-w0},{-w1,w0,0}};
    double W2[3][3];
    for (int i = 0; i < 3; i++)
        for (int j = 0; j < 3; j++) {
            double s2 = 0;
            for (int k = 0; k < 3; k++) s2 += Wm[i][k]*Wm[k][j];
            W2[i][j] = s2;
        }
    double dr[3][3];
    for (int i = 0; i < 3; i++)
        for (int j = 0; j < 3; j++)
            dr[i][j] = (i == j ? 1.0 : 0.0) + Af*Wm[i][j] + Bf*W2[i][j];
    double Rn[3][3];
    for (int i = 0; i < 3; i++)
        for (int j = 0; j < 3; j++) {
            double s2 = 0;
            for (int k = 0; k < 3; k++) s2 += dr[i][k] * (double)st[k*3+j];
            Rn[i][j] = s2;
        }
    for (int i = 0; i < 3; i++)
        for (int j = 0; j < 3; j++) st[14 + i*3 + j] = (float)Rn[i][j];
    for (int i = 0; i < 3; i++) {
        double s2 = 0;
        for (int k = 0; k < 3; k++) s2 += dr[i][k] * (double)st[9+k];
        st[23+i] = (float)(s2 + delta[i]);
    }
}

// ------------------------------------------------------------------- pass B
__global__ void k_passB(const float* __restrict__ qT, const float* __restrict__ feat0,
                        const float* __restrict__ pts0, const float* __restrict__ st,
                        float* __restrict__ ncost) {
    const int n = blockIdx.x;
    const int tid = threadIdx.x;
    const float p0 = pts0[n*3+0], p1 = pts0[n*3+1], p2 = pts0[n*3+2];
    // npts = pts0 @ R_new.T + t_new  (row i of R_new dotted with pts0)
    const float X = p0*st[14] + p1*st[15] + p2*st[16] + st[23];
    const float Y = p0*st[17] + p1*st[18] + p2*st[19] + st[24];
    const float Z = p0*st[20] + p1*st[21] + p2*st[22] + st[25];
    const float hx = st[32]*X + st[33]*Y + st[34]*Z;
    const float hy = st[35]*X + st[36]*Y + st[37]*Z;
    const float hz = st[38]*X + st[39]*Y + st[40]*Z;
    const float sr = st[43];
    const float u = hx / hz, v = hy / hz;
    int ix = (int)floorf(u / sr); ix = min(max(ix, 0), W_-1);
    int iy = (int)floorf(v / sr); iy = min(max(iy, 0), H_-1);
    const int pix = iy * W_ + ix;

    const float4* q4 = (const float4*)(qT + (size_t)pix * C_);
    const float4* f4 = (const float4*)(feat0 + (size_t)n * C_);
    float4 qv = q4[tid], fv = f4[tid];
    float cost = 0, e;
    e = qv.x - fv.x; cost += e*e;
    e = qv.y - fv.y; cost += e*e;
    e = qv.z - fv.z; cost += e*e;
    e = qv.w - fv.w; cost += e*e;
    cost = waveSum(cost);
    __shared__ float red[4];
    int wid = tid >> 6, lane = tid & 63;
    if (lane == 0) red[wid] = cost;
    __syncthreads();
    if (tid == 0) ncost[n] = red[0] + red[1] + red[2] + red[3];
}

// ------------------------------------------------------------ accept/reject
__global__ void k_decide(const float* __restrict__ ncost, float* __restrict__ st) {
    const int tid = threadIdx.x;
    double s = 0;
    for (int i = tid; i < N_; i += 256) s += (double)ncost[i];
    __shared__ double sd[256];
    sd[tid] = s;
    __syncthreads();
    for (int k = 128; k; k >>= 1) { if (tid < k) sd[tid] += sd[tid+k]; __syncthreads(); }
    if (tid == 0) {
        float nc = (float)(sd[0] / (double)N_);
        float prev = st[13], lam = st[12];
        bool bad = isnan(nc) || (st[72] != 0.f);
        bool worse = nc > prev;
        float lu = lam * (worse ? 10.f : 0.1f);
        lu = fminf(fmaxf(lu, 1e-6f), 100.f);
        st[12] = bad ? lam : lu;
        bool accept = !(worse || bad);
        if (accept) {
            for (int i = 0; i < 9; i++) st[i] = st[14+i];
            for (int i = 0; i < 3; i++) st[9+i] = st[23+i];
            st[13] = nc;
        }
    }
}

__global__ void k_out(const float* __restrict__ st, float* __restrict__ out) {
    int i = threadIdx.x;
    if (i < 12) out[i] = st[i];   // st[0..8]=R, st[9..11]=t -> contiguous
}

extern "C" void kernel_launch(void* const* d_in, const int* in_sizes, int n_in,
                              void* d_out, int out_size, void* d_ws, size_t ws_size,
                              hipStream_t stream) {
    const float* q   = (const float*)d_in[0];
    const float* r   = (const float*)d_in[1];
    const float* p2d = (const float*)d_in[2];
    const float* p3d = (const float*)d_in[3];
    const float* qf  = (const float*)d_in[4];
    const float* rf  = (const float*)d_in[5];
    const float* K1  = (const float*)d_in[6];
    const int*   srp = (const int*)d_in[7];

    float* ws = (float*)d_ws;
    size_t off = 0;
    float* qT    = ws + off; off += (size_t)HW_ * C_;   // 64 MB
    float* gxT   = ws + off; off += (size_t)HW_ * C_;   // 64 MB
    float* gyT   = ws + off; off += (size_t)HW_ * C_;   // 64 MB
    float* feat0 = ws + off; off += (size_t)N_ * C_;    // 32 MB
    float* pts0  = ws + off; off += 3 * N_;
    int*   pix0  = (int*)(ws + off); off += N_;
    float* parts = ws + off; off += (size_t)NCOMP * N_;
    float* ncost = ws + off; off += N_;
    float* st    = ws + off; off += 128;

    k_init<<<1, 1, 0, stream>>>(q, r, K1, srp, st);
    k_pts0<<<(N_ + 255) / 256, 256, 0, stream>>>(p3d, p2d, r, srp, pts0, pix0);
    // transpose reference into qT buffer (temporarily), gather feat0, then
    // overwrite qT with the query transpose + fused sobel.
    k_transpose<false><<<dim3(W_/64, H_, C_/64), 256, 0, stream>>>(rf, qT, nullptr, nullptr);
    k_feat0<<<N_, 256, 0, stream>>>(qT, pix0, feat0);
    k_transpose<true><<<dim3(W_/64, H_, C_/64), 256, 0, stream>>>(qf, qT, gxT, gyT);

    for (int it = 0; it < ITERS; it++) {
        k_passA<<<N_, 256, 0, stream>>>(qT, gxT, gyT, feat0, pts0, st, parts);
        k_reduce<<<NCOMP, 256, 0, stream>>>(parts, st);
        k_solve<<<1, 1, 0, stream>>>(st, it);
        k_passB<<<N_, 256, 0, stream>>>(qT, feat0, pts0, st, ncost);
        k_decide<<<1, 256, 0, stream>>>(ncost, st);
    }
    k_out<<<1, 64, 0, stream>>>(st, (float*)d_out);
}

// Round 2
// 1048.532 us; speedup vs baseline: 1.0626x; 1.0626x over previous
//
#include <hip/hip_runtime.h>
#include <math.h>

// Problem constants (fixed by setup_inputs)
constexpr int C_  = 1024;
constexpr int H_  = 128;
constexpr int W_  = 128;
constexpr int HW_ = H_ * W_;
constexpr int N_  = 8192;
constexpr int NCOMP = 28;      // cost, g[6], H upper-tri[21]
constexpr int ITERS = 10;

// state layout (floats):
//  0-8   R (row-major)
//  9-11  t
//  12    lam
//  13    prev
//  14-22 R_new
//  23-25 t_new
//  26-31 delta
//  32-40 K1
//  41 fx  42 fy  43 size_ratio (as float)
//  44-71 reduced sums: cost, g[6], H[21]
//  72    nan flag for delta

// ---------------------------------------------------------------- init pose
__global__ void k_init(const float* __restrict__ q, const float* __restrict__ r,
                       const float* __restrict__ K1, const int* __restrict__ srp,
                       float* __restrict__ st) {
    if (threadIdx.x != 0 || blockIdx.x != 0) return;
    // invert r_matrix (4x4) via Gauss-Jordan in double
    double a[4][8];
    for (int i = 0; i < 4; i++)
        for (int j = 0; j < 4; j++) { a[i][j] = r[i*4+j]; a[i][j+4] = (i == j) ? 1.0 : 0.0; }
    for (int col = 0; col < 4; col++) {
        int piv = col; double mx = fabs(a[col][col]);
        for (int i = col+1; i < 4; i++) if (fabs(a[i][col]) > mx) { mx = fabs(a[i][col]); piv = i; }
        if (piv != col) for (int j = 0; j < 8; j++) { double t = a[col][j]; a[col][j] = a[piv][j]; a[piv][j] = t; }
        double d = a[col][col];
        for (int j = 0; j < 8; j++) a[col][j] /= d;
        for (int i = 0; i < 4; i++) if (i != col) {
            double f = a[i][col];
            for (int j = 0; j < 8; j++) a[i][j] -= f * a[col][j];
        }
    }
    double rel[4][4];
    for (int i = 0; i < 4; i++)
        for (int j = 0; j < 4; j++) {
            double s = 0;
            for (int k = 0; k < 4; k++) s += (double)q[i*4+k] * a[k][j+4];
            rel[i][j] = s;
        }
    for (int i = 0; i < 3; i++)
        for (int j = 0; j < 3; j++) st[i*3+j] = (float)rel[i][j];
    st[9]  = (float)rel[3][0];
    st[10] = (float)rel[3][1];
    st[11] = (float)rel[3][2];
    st[12] = 0.01f;                 // LAMBDA0
    st[13] = __builtin_inff();      // prev
    for (int i = 0; i < 9; i++) st[32+i] = K1[i];
    st[41] = K1[0]; st[42] = K1[4];
    st[43] = (float)srp[0];
}

// ------------------------------------------------------- pts0 + pix0 (once)
__global__ void k_pts0(const float* __restrict__ p3d, const float* __restrict__ p2d,
                       const float* __restrict__ r, const int* __restrict__ srp,
                       float* __restrict__ pts0, int* __restrict__ pix0) {
    int n = blockIdx.x * blockDim.x + threadIdx.x;
    if (n >= N_) return;
    float sr = (float)srp[0];
    float ph[4] = { p3d[n*3+0], p3d[n*3+1], p3d[n*3+2], 1.f };
    float h[4];
    for (int i = 0; i < 4; i++) {
        float s = 0.f;
        for (int j = 0; j < 4; j++) s += r[i*4+j] * ph[j];
        h[i] = s;
    }
    pts0[n*3+0] = h[0]/h[3];
    pts0[n*3+1] = h[1]/h[3];
    pts0[n*3+2] = h[2]/h[3];
    int ix = (int)floorf(p2d[n*2+0] / sr); ix = min(max(ix, 0), W_-1);
    int iy = (int)floorf(p2d[n*2+1] / sr); iy = min(max(iy, 0), H_-1);
    pix0[n] = iy * W_ + ix;
}

// -------------------------------- transpose (C,H,W)->(HW,C), optional sobel
// tile: 16 channels x 8 rows x 32 cols per block. 22.4KB LDS -> 7 blocks/CU.
// y-halo amortized over 8 rows (1.25x fetch). odd channel stride (351) kills
// bank conflicts. sobel uses register-rolling window: 3 LDS reads/output.
template <bool SOBEL>
__global__ void k_transpose2(const float* __restrict__ src, float* __restrict__ dq,
                             float* __restrict__ dgx, float* __restrict__ dgy) {
    constexpr int CT = 16, YT = 8, XT = 32;
    constexpr int RS = YT + 2;        // 10 halo rows
    constexpr int CS = XT + 2;        // 34 halo cols
    constexpr int PCS = 35;           // padded col stride
    constexpr int CHS = RS * PCS + 1; // 351 (odd) per-channel stride
    __shared__ float lds[CT * CHS];
    const int x0 = blockIdx.x * XT;
    const int y0 = blockIdx.y * YT;
    const int cc = blockIdx.z * CT;
    const int tid = threadIdx.x;
    for (int idx = tid; idx < CT * RS * CS; idx += 256) {
        int c   = idx / (RS * CS);
        int rem = idx % (RS * CS);
        int r   = rem / CS;
        int x   = rem % CS;
        int gy  = y0 + r - 1;
        int gx  = x0 + x - 1;
        float v = 0.f;
        if (gy >= 0 && gy < H_ && gx >= 0 && gx < W_)
            v = src[(size_t)(cc + c) * HW_ + gy * W_ + gx];
        lds[c * CHS + r * PCS + x] = v;
    }
    __syncthreads();
    const int c       = tid & 15;
    const int s       = tid >> 4;        // 0..15
    const int row     = s >> 1;          // 0..7
    const int colbase = (s & 1) * 16;    // 0 or 16
    const float* Lt = &lds[c * CHS + row * PCS + colbase];
    const float* Lm = Lt + PCS;
    const float* Lb = Lm + PCS;
    size_t o = ((size_t)((y0 + row) * W_ + x0 + colbase)) * C_ + cc + c;
    if (!SOBEL) {
        for (int cx = 0; cx < 16; cx++, o += C_)
            dq[o] = Lm[cx + 1];
    } else {
        float t0l = Lt[0], t0m = Lt[1];
        float t1l = Lm[0], t1m = Lm[1];
        float t2l = Lb[0], t2m = Lb[1];
        for (int cx = 0; cx < 16; cx++, o += C_) {
            float t0r = Lt[cx + 2];
            float t1r = Lm[cx + 2];
            float t2r = Lb[cx + 2];
            dq[o]  = t1m;
            dgx[o] = (t0r - t0l) + 2.f*(t1r - t1l) + (t2r - t2l);
            dgy[o] = (t2l + 2.f*t2m + t2r) - (t0l + 2.f*t0m + t0r);
            t0l = t0m; t0m = t0r;
            t1l = t1m; t1m = t1r;
            t2l = t2m; t2m = t2r;
        }
    }
}

// ---------------------------------------------------- feat0 gather (coalesced)
__global__ void k_feat0(const float* __restrict__ rT, const int* __restrict__ pix0,
                        float* __restrict__ feat0) {
    int n = blockIdx.x;
    const float4* s = (const float4*)(rT + (size_t)pix0[n] * C_);
    float4* d = (float4*)(feat0 + (size_t)n * C_);
    d[threadIdx.x] = s[threadIdx.x];
}

__device__ inline float waveSum(float v) {
    for (int o = 32; o; o >>= 1) v += __shfl_down(v, o, 64);
    return v;
}

// ------------------------------------------------------------------- pass A
__global__ void k_passA(const float* __restrict__ qT, const float* __restrict__ gxT,
                        const float* __restrict__ gyT, const float* __restrict__ feat0,
                        const float* __restrict__ pts0, const float* __restrict__ st,
                        float* __restrict__ parts) {
    const int n = blockIdx.x;
    const int tid = threadIdx.x;
    const float p0 = pts0[n*3+0], p1 = pts0[n*3+1], p2 = pts0[n*3+2];
    // pts1 = pts0 @ R + t
    const float X = p0*st[0] + p1*st[3] + p2*st[6] + st[9];
    const float Y = p0*st[1] + p1*st[4] + p2*st[7] + st[10];
    const float Z = p0*st[2] + p1*st[5] + p2*st[8] + st[11];
    const float hx = st[32]*X + st[33]*Y + st[34]*Z;
    const float hy = st[35]*X + st[36]*Y + st[37]*Z;
    const float hz = st[38]*X + st[39]*Y + st[40]*Z;
    const float sr = st[43];
    const float u = hx / hz, v = hy / hz;
    int ix = (int)floorf(u / sr); ix = min(max(ix, 0), W_-1);
    int iy = (int)floorf(v / sr); iy = min(max(iy, 0), H_-1);
    const int pix = iy * W_ + ix;

    const float4* q4 = (const float4*)(qT  + (size_t)pix * C_);
    const float4* g4 = (const float4*)(gxT + (size_t)pix * C_);
    const float4* h4 = (const float4*)(gyT + (size_t)pix * C_);
    const float4* f4 = (const float4*)(feat0 + (size_t)n * C_);
    float4 qv = q4[tid], gv = g4[tid], yv = h4[tid], fv = f4[tid];

    float cost = 0, bx = 0, by = 0, mxx = 0, mxy = 0, myy = 0;
    {
        float e;
        e = qv.x - fv.x; cost += e*e; bx += gv.x*e; by += yv.x*e; mxx += gv.x*gv.x; mxy += gv.x*yv.x; myy += yv.x*yv.x;
        e = qv.y - fv.y; cost += e*e; bx += gv.y*e; by += yv.y*e; mxx += gv.y*gv.y; mxy += gv.y*yv.y; myy += yv.y*yv.y;
        e = qv.z - fv.z; cost += e*e; bx += gv.z*e; by += yv.z*e; mxx += gv.z*gv.z; mxy += gv.z*yv.z; myy += yv.z*yv.z;
        e = qv.w - fv.w; cost += e*e; bx += gv.w*e; by += yv.w*e; mxx += gv.w*gv.w; mxy += gv.w*yv.w; myy += yv.w*yv.w;
    }
    cost = waveSum(cost); bx = waveSum(bx); by = waveSum(by);
    mxx = waveSum(mxx); mxy = waveSum(mxy); myy = waveSum(myy);

    __shared__ float red[4][6];
    int wid = tid >> 6, lane = tid & 63;
    if (lane == 0) {
        red[wid][0] = cost; red[wid][1] = bx;  red[wid][2] = by;
        red[wid][3] = mxx;  red[wid][4] = mxy; red[wid][5] = myy;
    }
    __syncthreads();
    if (tid == 0) {
        cost = red[0][0]+red[1][0]+red[2][0]+red[3][0];
        bx   = red[0][1]+red[1][1]+red[2][1]+red[3][1];
        by   = red[0][2]+red[1][2]+red[2][2]+red[3][2];
        mxx  = red[0][3]+red[1][3]+red[2][3]+red[3][3];
        mxy  = red[0][4]+red[1][4]+red[2][4]+red[3][4];
        myy  = red[0][5]+red[1][5]+red[2][5]+red[3][5];

        const float fx = st[41], fy = st[42];
        const float s = 1.f / (Z * sr);
        const float jh00 = fx, jh02 = -fx * X / Z;
        const float jh11 = fy, jh12 = -fy * Y / Z;
        // J_p_T rows: [1,0,0,0,Z,-Y], [0,1,0,-Z,0,X], [0,0,1,Y,-X,0]
        float A0[6], A1[6];
        A0[0] = s*jh00; A0[1] = 0.f;    A0[2] = s*jh02;
        A0[3] = s*(jh02*Y); A0[4] = s*(jh00*Z - jh02*X); A0[5] = s*(-jh00*Y);
        A1[0] = 0.f;    A1[1] = s*jh11; A1[2] = s*jh12;
        A1[3] = s*(-jh11*Z + jh12*Y); A1[4] = s*(-jh12*X); A1[5] = s*(jh11*X);

        parts[0*N_ + n] = cost;
        for (int k = 0; k < 6; k++) parts[(1+k)*N_ + n] = A0[k]*bx + A1[k]*by;
        int idx = 7;
        for (int k = 0; k < 6; k++)
            for (int l = k; l < 6; l++) {
                parts[idx*N_ + n] = A0[k]*A0[l]*mxx + (A0[k]*A1[l] + A1[k]*A0[l])*mxy + A1[k]*A1[l]*myy;
                idx++;
            }
    }
}

// --------------------------- fused deterministic reduction + LM solve/update
// one block, 16 waves; wave w reduces comps {w, w+16}; thread 0 then solves.
__global__ void k_reduce_solve(const float* __restrict__ parts, float* __restrict__ st,
                               int iter) {
    const int tid = threadIdx.x;
    const int w = tid >> 6, lane = tid & 63;
    for (int comp = w; comp < NCOMP; comp += 16) {
        const float4* p4 = (const float4*)(parts + (size_t)comp * N_);
        double s = 0;
        for (int i = lane; i < N_/4; i += 64) {
            float4 v = p4[i];
            s += (double)v.x + (double)v.y + (double)v.z + (double)v.w;
        }
        for (int o = 32; o; o >>= 1) s += __shfl_down(s, o, 64);
        if (lane == 0) st[44 + comp] = (float)s;
    }
    __syncthreads();
    if (tid != 0) return;

    double costsum = st[44];
    if (iter == 0) st[13] = (float)(costsum / (double)N_);
    double g[6];
    for (int k = 0; k < 6; k++) g[k] = st[45+k];
    double Hs[6][6];
    int idx = 51;
    for (int k = 0; k < 6; k++)
        for (int l = k; l < 6; l++) { Hs[k][l] = st[idx]; Hs[l][k] = st[idx]; idx++; }
    double lam = st[12];
    double M[6][7];
    for (int i = 0; i < 6; i++) {
        for (int j = 0; j < 6; j++) M[i][j] = Hs[i][j];
        M[i][i] += (Hs[i][i] + 1e-9) * lam;
        M[i][6] = -g[i];
    }
    for (int col = 0; col < 6; col++) {
        int piv = col; double mx = fabs(M[col][col]);
        for (int i = col+1; i < 6; i++) if (fabs(M[i][col]) > mx) { mx = fabs(M[i][col]); piv = i; }
        if (piv != col) for (int j = col; j < 7; j++) { double t = M[col][j]; M[col][j] = M[piv][j]; M[piv][j] = t; }
        double d = M[col][col];
        for (int j = col; j < 7; j++) M[col][j] /= d;
        for (int i = 0; i < 6; i++) if (i != col) {
            double f = M[i][col];
            if (f != 0.0) for (int j = col; j < 7; j++) M[i][j] -= f * M[col][j];
        }
    }
    double delta[6];
    int bad = 0;
    for (int i = 0; i < 6; i++) {
        delta[i] = M[i][6];
        st[26+i] = (float)delta[i];
        if (isnan(st[26+i])) bad = 1;
    }
    st[72] = (float)bad;
    double w0 = delta[3], w1 = delta[4], w2 = delta[5];
    double th2 = w0*w0 + w1*w1 + w2*w2 + 1e-12;
    double th = sqrt(th2);
    double Af = sin(th) / th, Bf = (1.0 - cos(th)) / th2;
    double Wm[3][3] = {{0,-w2,w1},{w2,0,-w0},{-w1,w0,0}};
    double W2[3][3];
    for (int i = 0; i < 3; i++)
        for (int j = 0; j < 3; j++) {
            double s2 = 0;
            for (int k = 0; k < 3; k++) s2 += Wm[i][k]*Wm[k][j];
            W2[i][j] = s2;
        }
    double dr[3][3];
    for (int i = 0; i < 3; i++)
        for (int j = 0; j < 3; j++)
            dr[i][j] = (i == j ? 1.0 : 0.0) + Af*Wm[i][j] + Bf*W2[i][j];
    double Rn[3][3];
    for (int i = 0; i < 3; i++)
        for (int j = 0; j < 3; j++) {
            double s2 = 0;
            for (int k = 0; k < 3; k++) s2 += dr[i][k] * (double)st[k*3+j];
            Rn[i][j] = s2;
        }
    for (int i = 0; i < 3; i++)
        for (int j = 0; j < 3; j++) st[14 + i*3 + j] = (float)Rn[i][j];
    for (int i = 0; i < 3; i++) {
        double s2 = 0;
        for (int k = 0; k < 3; k++) s2 += dr[i][k] * (double)st[9+k];
        st[23+i] = (float)(s2 + delta[i]);
    }
}

// ------------------------------------------------------------------- pass B
__global__ void k_passB(const float* __restrict__ qT, const float* __restrict__ feat0,
                        const float* __restrict__ pts0, const float* __restrict__ st,
                        float* __restrict__ ncost) {
    const int n = blockIdx.x;
    const int tid = threadIdx.x;
    const float p0 = pts0[n*3+0], p1 = pts0[n*3+1], p2 = pts0[n*3+2];
    // npts = pts0 @ R_new.T + t_new  (row i of R_new dotted with pts0)
    const float X = p0*st[14] + p1*st[15] + p2*st[16] + st[23];
    const float Y = p0*st[17] + p1*st[18] + p2*st[19] + st[24];
    const float Z = p0*st[20] + p1*st[21] + p2*st[22] + st[25];
    const float hx = st[32]*X + st[33]*Y + st[34]*Z;
    const float hy = st[35]*X + st[36]*Y + st[37]*Z;
    const float hz = st[38]*X + st[39]*Y + st[40]*Z;
    const float sr = st[43];
    const float u = hx / hz, v = hy / hz;
    int ix = (int)floorf(u / sr); ix = min(max(ix, 0), W_-1);
    int iy = (int)floorf(v / sr); iy = min(max(iy, 0), H_-1);
    const int pix = iy * W_ + ix;

    const float4* q4 = (const float4*)(qT + (size_t)pix * C_);
    const float4* f4 = (const float4*)(feat0 + (size_t)n * C_);
    float4 qv = q4[tid], fv = f4[tid];
    float cost = 0, e;
    e = qv.x - fv.x; cost += e*e;
    e = qv.y - fv.y; cost += e*e;
    e = qv.z - fv.z; cost += e*e;
    e = qv.w - fv.w; cost += e*e;
    cost = waveSum(cost);
    __shared__ float red[4];
    int wid = tid >> 6, lane = tid & 63;
    if (lane == 0) red[wid] = cost;
    __syncthreads();
    if (tid == 0) ncost[n] = red[0] + red[1] + red[2] + red[3];
}

// ------------------------------------------------------------ accept/reject
__global__ void k_decide(const float* __restrict__ ncost, float* __restrict__ st) {
    const int tid = threadIdx.x;
    double s = 0;
    for (int i = tid; i < N_; i += 256) s += (double)ncost[i];
    __shared__ double sd[256];
    sd[tid] = s;
    __syncthreads();
    for (int k = 128; k; k >>= 1) { if (tid < k) sd[tid] += sd[tid+k]; __syncthreads(); }
    if (tid == 0) {
        float nc = (float)(sd[0] / (double)N_);
        float prev = st[13], lam = st[12];
        bool bad = isnan(nc) || (st[72] != 0.f);
        bool worse = nc > prev;
        float lu = lam * (worse ? 10.f : 0.1f);
        lu = fminf(fmaxf(lu, 1e-6f), 100.f);
        st[12] = bad ? lam : lu;
        bool accept = !(worse || bad);
        if (accept) {
            for (int i = 0; i < 9; i++) st[i] = st[14+i];
            for (int i = 0; i < 3; i++) st[9+i] = st[23+i];
            st[13] = nc;
        }
    }
}

__global__ void k_out(const float* __restrict__ st, float* __restrict__ out) {
    int i = threadIdx.x;
    if (i < 12) out[i] = st[i];   // st[0..8]=R, st[9..11]=t -> contiguous
}

extern "C" void kernel_launch(void* const* d_in, const int* in_sizes, int n_in,
                              void* d_out, int out_size, void* d_ws, size_t ws_size,
                              hipStream_t stream) {
    const float* q   = (const float*)d_in[0];
    const float* r   = (const float*)d_in[1];
    const float* p2d = (const float*)d_in[2];
    const float* p3d = (const float*)d_in[3];
    const float* qf  = (const float*)d_in[4];
    const float* rf  = (const float*)d_in[5];
    const float* K1  = (const float*)d_in[6];
    const int*   srp = (const int*)d_in[7];

    float* ws = (float*)d_ws;
    size_t off = 0;
    float* qT    = ws + off; off += (size_t)HW_ * C_;   // 64 MB
    float* gxT   = ws + off; off += (size_t)HW_ * C_;   // 64 MB
    float* gyT   = ws + off; off += (size_t)HW_ * C_;   // 64 MB
    float* feat0 = ws + off; off += (size_t)N_ * C_;    // 32 MB
    float* pts0  = ws + off; off += 3 * N_;
    int*   pix0  = (int*)(ws + off); off += N_;
    float* parts = ws + off; off += (size_t)NCOMP * N_;
    float* ncost = ws + off; off += N_;
    float* st    = ws + off; off += 128;

    k_init<<<1, 1, 0, stream>>>(q, r, K1, srp, st);
    k_pts0<<<(N_ + 255) / 256, 256, 0, stream>>>(p3d, p2d, r, srp, pts0, pix0);
    // transpose reference into qT buffer (temporarily), gather feat0, then
    // overwrite qT with the query transpose + fused sobel.
    k_transpose2<false><<<dim3(W_/32, H_/8, C_/16), 256, 0, stream>>>(rf, qT, nullptr, nullptr);
    k_feat0<<<N_, 256, 0, stream>>>(qT, pix0, feat0);
    k_transpose2<true><<<dim3(W_/32, H_/8, C_/16), 256, 0, stream>>>(qf, qT, gxT, gyT);

    for (int it = 0; it < ITERS; it++) {
        k_passA<<<N_, 256, 0, stream>>>(qT, gxT, gyT, feat0, pts0, st, parts);
        k_reduce_solve<<<1, 1024, 0, stream>>>(parts, st, it);
        k_passB<<<N_, 256, 0, stream>>>(qT, feat0, pts0, st, ncost);
        k_decide<<<1, 256, 0, stream>>>(ncost, st);
    }
    k_out<<<1, 64, 0, stream>>>(st, (float*)d_out);
}

// Round 3
// 851.776 us; speedup vs baseline: 1.3081x; 1.2310x over previous
//
#include <hip/hip_runtime.h>
#include <math.h>

// Problem constants (fixed by setup_inputs)
constexpr int C_  = 1024;
constexpr int H_  = 128;
constexpr int W_  = 128;
constexpr int HW_ = H_ * W_;
constexpr int N_  = 8192;
constexpr int NCOMP = 28;      // cost, g[6], H upper-tri[21]
constexpr int ITERS = 10;
constexpr int NB_ = 2048;      // blocks for wave-per-point kernels (4 pts/block)

// state layout (floats):
//  0-8   R (row-major)   9-11 t   12 lam   13 prev
//  14-22 R_new   23-25 t_new   26-31 delta
//  32-40 K1   41 fx   42 fy   43 size_ratio
//  44-71 reduced sums: cost, g[6], H[21]   72 nan flag for delta

// ----------------------------------------------- setup: init pose + pts0/pix0
__global__ void k_setup(const float* __restrict__ q, const float* __restrict__ r,
                        const float* __restrict__ K1, const int* __restrict__ srp,
                        const float* __restrict__ p3d, const float* __restrict__ p2d,
                        float* __restrict__ st, float* __restrict__ pts0,
                        int* __restrict__ pix0) {
    int n = blockIdx.x * blockDim.x + threadIdx.x;
    if (n < N_) {
        float sr = (float)srp[0];
        float ph[4] = { p3d[n*3+0], p3d[n*3+1], p3d[n*3+2], 1.f };
        float h[4];
        for (int i = 0; i < 4; i++) {
            float s = 0.f;
            for (int j = 0; j < 4; j++) s += r[i*4+j] * ph[j];
            h[i] = s;
        }
        pts0[n*3+0] = h[0]/h[3];
        pts0[n*3+1] = h[1]/h[3];
        pts0[n*3+2] = h[2]/h[3];
        int ix = (int)floorf(p2d[n*2+0] / sr); ix = min(max(ix, 0), W_-1);
        int iy = (int)floorf(p2d[n*2+1] / sr); iy = min(max(iy, 0), H_-1);
        pix0[n] = iy * W_ + ix;
    }
    if (blockIdx.x == 0 && threadIdx.x == 0) {
        // invert r_matrix (4x4) via Gauss-Jordan in double
        double a[4][8];
        for (int i = 0; i < 4; i++)
            for (int j = 0; j < 4; j++) { a[i][j] = r[i*4+j]; a[i][j+4] = (i == j) ? 1.0 : 0.0; }
        for (int col = 0; col < 4; col++) {
            int piv = col; double mx = fabs(a[col][col]);
            for (int i = col+1; i < 4; i++) if (fabs(a[i][col]) > mx) { mx = fabs(a[i][col]); piv = i; }
            if (piv != col) for (int j = 0; j < 8; j++) { double t = a[col][j]; a[col][j] = a[piv][j]; a[piv][j] = t; }
            double d = a[col][col];
            for (int j = 0; j < 8; j++) a[col][j] /= d;
            for (int i = 0; i < 4; i++) if (i != col) {
                double f = a[i][col];
                for (int j = 0; j < 8; j++) a[i][j] -= f * a[col][j];
            }
        }
        double rel[4][4];
        for (int i = 0; i < 4; i++)
            for (int j = 0; j < 4; j++) {
                double s = 0;
                for (int k = 0; k < 4; k++) s += (double)q[i*4+k] * a[k][j+4];
                rel[i][j] = s;
            }
        for (int i = 0; i < 3; i++)
            for (int j = 0; j < 3; j++) st[i*3+j] = (float)rel[i][j];
        st[9]  = (float)rel[3][0];
        st[10] = (float)rel[3][1];
        st[11] = (float)rel[3][2];
        st[12] = 0.01f;                 // LAMBDA0
        st[13] = __builtin_inff();      // prev
        for (int i = 0; i < 9; i++) st[32+i] = K1[i];
        st[41] = K1[0]; st[42] = K1[4];
        st[43] = (float)srp[0];
    }
}

// -------------------------------- transpose (C,H,W)->(HW,C), optional sobel
// tile: 16 channels x 4 rows x 32 cols. 13.2KB LDS -> 8 blocks/CU (wave cap).
// y-halo amortized over 4 rows (1.5x). odd channel stride (211) for banks.
template <bool SOBEL>
__global__ void k_transpose2(const float* __restrict__ src, float* __restrict__ dq,
                             float* __restrict__ dgx, float* __restrict__ dgy) {
    constexpr int CT = 16, YT = 4, XT = 32;
    constexpr int RS = YT + 2;        // 6 halo rows
    constexpr int CS = XT + 2;        // 34 halo cols
    constexpr int PCS = 35;           // padded col stride
    constexpr int CHS = RS * PCS + 1; // 211 (odd) per-channel stride
    __shared__ float lds[CT * CHS];
    const int x0 = blockIdx.x * XT;
    const int y0 = blockIdx.y * YT;
    const int cc = blockIdx.z * CT;
    const int tid = threadIdx.x;
    for (int idx = tid; idx < CT * RS * CS; idx += 256) {
        int c   = idx / (RS * CS);
        int rem = idx % (RS * CS);
        int r   = rem / CS;
        int x   = rem % CS;
        int gy  = y0 + r - 1;
        int gx  = x0 + x - 1;
        float v = 0.f;
        if (gy >= 0 && gy < H_ && gx >= 0 && gx < W_)
            v = src[(size_t)(cc + c) * HW_ + gy * W_ + gx];
        lds[c * CHS + r * PCS + x] = v;
    }
    __syncthreads();
    const int c       = tid & 15;
    const int s       = tid >> 4;        // 0..15
    const int row     = s >> 2;          // 0..3
    const int colbase = (s & 3) * 8;     // 0,8,16,24
    const float* Lt = &lds[c * CHS + row * PCS + colbase];
    const float* Lm = Lt + PCS;
    const float* Lb = Lm + PCS;
    size_t o = ((size_t)((y0 + row) * W_ + x0 + colbase)) * C_ + cc + c;
    if (!SOBEL) {
        for (int cx = 0; cx < 8; cx++, o += C_)
            dq[o] = Lm[cx + 1];
    } else {
        float t0l = Lt[0], t0m = Lt[1];
        float t1l = Lm[0], t1m = Lm[1];
        float t2l = Lb[0], t2m = Lb[1];
        for (int cx = 0; cx < 8; cx++, o += C_) {
            float t0r = Lt[cx + 2];
            float t1r = Lm[cx + 2];
            float t2r = Lb[cx + 2];
            dq[o]  = t1m;
            dgx[o] = (t0r - t0l) + 2.f*(t1r - t1l) + (t2r - t2l);
            dgy[o] = (t2l + 2.f*t2m + t2r) - (t0l + 2.f*t0m + t0r);
            t0l = t0m; t0m = t0r;
            t1l = t1m; t1m = t1r;
            t2l = t2m; t2m = t2r;
        }
    }
}

// ----------------------------------- feat0 gather, wave-per-point (coalesced)
__global__ __launch_bounds__(256) void k_feat0(const float* __restrict__ rT,
                                               const int* __restrict__ pix0,
                                               float* __restrict__ feat0) {
    const int w = threadIdx.x >> 6, lane = threadIdx.x & 63;
    const int n = blockIdx.x * 4 + w;
    const float4* s = (const float4*)(rT + (size_t)pix0[n] * C_);
    float4* d = (float4*)(feat0 + (size_t)n * C_);
#pragma unroll
    for (int i = 0; i < 4; i++) d[i*64 + lane] = s[i*64 + lane];
}

__device__ inline float sel6(int k, float v0, float v1, float v2,
                             float v3, float v4, float v5) {
    return k==0 ? v0 : k==1 ? v1 : k==2 ? v2 : k==3 ? v3 : k==4 ? v4 : v5;
}

// -------------------------------------------------- pass A (wave-per-point)
__global__ __launch_bounds__(256) void k_passA(const float* __restrict__ qT,
        const float* __restrict__ gxT, const float* __restrict__ gyT,
        const float* __restrict__ feat0, const float* __restrict__ pts0,
        const float* __restrict__ st, float* __restrict__ partial) {
    const int w = threadIdx.x >> 6, lane = threadIdx.x & 63;
    const int n = blockIdx.x * 4 + w;
    const float p0 = pts0[n*3+0], p1 = pts0[n*3+1], p2 = pts0[n*3+2];
    // pts1 = pts0 @ R + t (column-dot)
    const float X = p0*st[0] + p1*st[3] + p2*st[6] + st[9];
    const float Y = p0*st[1] + p1*st[4] + p2*st[7] + st[10];
    const float Z = p0*st[2] + p1*st[5] + p2*st[8] + st[11];
    const float hx = st[32]*X + st[33]*Y + st[34]*Z;
    const float hy = st[35]*X + st[36]*Y + st[37]*Z;
    const float hz = st[38]*X + st[39]*Y + st[40]*Z;
    const float sr = st[43];
    const float u = hx / hz, v = hy / hz;
    int ix = (int)floorf(u / sr); ix = min(max(ix, 0), W_-1);
    int iy = (int)floorf(v / sr); iy = min(max(iy, 0), H_-1);
    const int pix = iy * W_ + ix;

    const float4* q4 = (const float4*)(qT  + (size_t)pix * C_);
    const float4* g4 = (const float4*)(gxT + (size_t)pix * C_);
    const float4* h4 = (const float4*)(gyT + (size_t)pix * C_);
    const float4* f4 = (const float4*)(feat0 + (size_t)n * C_);

    float cost = 0, bx = 0, by = 0, mxx = 0, mxy = 0, myy = 0;
#pragma unroll
    for (int i = 0; i < 4; i++) {
        float4 qv = q4[i*64 + lane], gv = g4[i*64 + lane];
        float4 yv = h4[i*64 + lane], fv = f4[i*64 + lane];
        float e;
        e = qv.x - fv.x; cost += e*e; bx += gv.x*e; by += yv.x*e; mxx += gv.x*gv.x; mxy += gv.x*yv.x; myy += yv.x*yv.x;
        e = qv.y - fv.y; cost += e*e; bx += gv.y*e; by += yv.y*e; mxx += gv.y*gv.y; mxy += gv.y*yv.y; myy += yv.y*yv.y;
        e = qv.z - fv.z; cost += e*e; bx += gv.z*e; by += yv.z*e; mxx += gv.z*gv.z; mxy += gv.z*yv.z; myy += yv.z*yv.z;
        e = qv.w - fv.w; cost += e*e; bx += gv.w*e; by += yv.w*e; mxx += gv.w*gv.w; mxy += gv.w*yv.w; myy += yv.w*yv.w;
    }
    // butterfly all-reduce so every lane has the 6 sums
#pragma unroll
    for (int off = 32; off; off >>= 1) {
        cost += __shfl_xor(cost, off, 64);
        bx   += __shfl_xor(bx,   off, 64);
        by   += __shfl_xor(by,   off, 64);
        mxx  += __shfl_xor(mxx,  off, 64);
        mxy  += __shfl_xor(mxy,  off, 64);
        myy  += __shfl_xor(myy,  off, 64);
    }

    // A matrix (2x6) = J_h_p @ J_p_T / (z*sr), same on all lanes
    const float fx = st[41], fy = st[42];
    const float sc = 1.f / (Z * sr);
    const float jh00 = fx, jh02 = -fx * X / Z;
    const float jh11 = fy, jh12 = -fy * Y / Z;
    const float a00 = sc*jh00, a01 = 0.f,     a02 = sc*jh02;
    const float a03 = sc*(jh02*Y), a04 = sc*(jh00*Z - jh02*X), a05 = sc*(-jh00*Y);
    const float a10 = 0.f,     a11 = sc*jh11, a12 = sc*jh12;
    const float a13 = sc*(-jh11*Z + jh12*Y), a14 = sc*(-jh12*X), a15 = sc*(jh11*X);

    float val = 0.f;
    const int t = lane;
    if (t == 0) {
        val = cost;
    } else if (t < 7) {
        int k = t - 1;
        val = sel6(k,a00,a01,a02,a03,a04,a05)*bx + sel6(k,a10,a11,a12,a13,a14,a15)*by;
    } else if (t < NCOMP) {
        int idx = t - 7, k = 0;
        while (idx >= 6 - k) { idx -= 6 - k; k++; }
        int l = k + idx;
        float A0k = sel6(k,a00,a01,a02,a03,a04,a05);
        float A1k = sel6(k,a10,a11,a12,a13,a14,a15);
        float A0l = sel6(l,a00,a01,a02,a03,a04,a05);
        float A1l = sel6(l,a10,a11,a12,a13,a14,a15);
        val = A0k*A0l*mxx + (A0k*A1l + A1k*A0l)*mxy + A1k*A1l*myy;
    }

    __shared__ float pl[4][NCOMP];
    if (t < NCOMP) pl[w][t] = val;
    __syncthreads();
    if (threadIdx.x < NCOMP)
        partial[(size_t)threadIdx.x * NB_ + blockIdx.x] =
            pl[0][threadIdx.x] + pl[1][threadIdx.x] + pl[2][threadIdx.x] + pl[3][threadIdx.x];
}

// --------------------------- fused deterministic reduction + LM solve/update
__global__ void k_RS(const float* __restrict__ partial, float* __restrict__ st,
                     int iter) {
    const int tid = threadIdx.x;
    const int w = tid >> 6, lane = tid & 63;
    for (int comp = w; comp < NCOMP; comp += 16) {
        double s = 0;
#pragma unroll 4
        for (int i = 0; i < NB_/64; i++)
            s += (double)partial[(size_t)comp * NB_ + i*64 + lane];
        for (int off = 32; off; off >>= 1) s += __shfl_down(s, off, 64);
        if (lane == 0) st[44 + comp] = (float)s;
    }
    __syncthreads();
    if (tid != 0) return;

    double costsum = st[44];
    if (iter == 0) st[13] = (float)(costsum / (double)N_);
    double g[6];
    for (int k = 0; k < 6; k++) g[k] = st[45+k];
    double Hs[6][6];
    int idx = 51;
    for (int k = 0; k < 6; k++)
        for (int l = k; l < 6; l++) { Hs[k][l] = st[idx]; Hs[l][k] = st[idx]; idx++; }
    double lam = st[12];
    double M[6][7];
    for (int i = 0; i < 6; i++) {
        for (int j = 0; j < 6; j++) M[i][j] = Hs[i][j];
        M[i][i] += (Hs[i][i] + 1e-9) * lam;
        M[i][6] = -g[i];
    }
    for (int col = 0; col < 6; col++) {
        int piv = col; double mx = fabs(M[col][col]);
        for (int i = col+1; i < 6; i++) if (fabs(M[i][col]) > mx) { mx = fabs(M[i][col]); piv = i; }
        if (piv != col) for (int j = col; j < 7; j++) { double t = M[col][j]; M[col][j] = M[piv][j]; M[piv][j] = t; }
        double d = M[col][col];
        for (int j = col; j < 7; j++) M[col][j] /= d;
        for (int i = 0; i < 6; i++) if (i != col) {
            double f = M[i][col];
            if (f != 0.0) for (int j = col; j < 7; j++) M[i][j] -= f * M[col][j];
        }
    }
    double delta[6];
    int bad = 0;
    for (int i = 0; i < 6; i++) {
        delta[i] = M[i][6];
        st[26+i] = (float)delta[i];
        if (isnan(st[26+i])) bad = 1;
    }
    st[72] = (float)bad;
    double w0 = delta[3], w1 = delta[4], w2 = delta[5];
    double th2 = w0*w0 + w1*w1 + w2*w2 + 1e-12;
    double th = sqrt(th2);
    double Af = sin(th) / th, Bf = (1.0 - cos(th)) / th2;
    double Wm[3][3] = {{0,-w2,w1},{w2,0,-w0},{-w1,w0,0}};
    double W2[3][3];
    for (int i = 0; i < 3; i++)
        for (int j = 0; j < 3; j++) {
            double s2 = 0;
            for (int k = 0; k < 3; k++) s2 += Wm[i][k]*Wm[k][j];
            W2[i][j] = s2;
        }
    double dr[3][3];
    for (int i = 0; i < 3; i++)
        for (int j = 0; j < 3; j++)
            dr[i][j] = (i == j ? 1.0 : 0.0) + Af*Wm[i][j] + Bf*W2[i][j];
    double Rn[3][3];
    for (int i = 0; i < 3; i++)
        for (int j = 0; j < 3; j++) {
            double s2 = 0;
            for (int k = 0; k < 3; k++) s2 += dr[i][k] * (double)st[k*3+j];
            Rn[i][j] = s2;
        }
    for (int i = 0; i < 3; i++)
        for (int j = 0; j < 3; j++) st[14 + i*3 + j] = (float)Rn[i][j];
    for (int i = 0; i < 3; i++) {
        double s2 = 0;
        for (int k = 0; k < 3; k++) s2 += dr[i][k] * (double)st[9+k];
        st[23+i] = (float)(s2 + delta[i]);
    }
}

// -------------------------------------------------- pass B (wave-per-point)
__global__ __launch_bounds__(256) void k_passB(const float* __restrict__ qT,
        const float* __restrict__ feat0, const float* __restrict__ pts0,
        const float* __restrict__ st, float* __restrict__ ncostp) {
    const int w = threadIdx.x >> 6, lane = threadIdx.x & 63;
    const int n = blockIdx.x * 4 + w;
    const float p0 = pts0[n*3+0], p1 = pts0[n*3+1], p2 = pts0[n*3+2];
    // npts = pts0 @ R_new.T + t_new (row-dot)
    const float X = p0*st[14] + p1*st[15] + p2*st[16] + st[23];
    const float Y = p0*st[17] + p1*st[18] + p2*st[19] + st[24];
    const float Z = p0*st[20] + p1*st[21] + p2*st[22] + st[25];
    const float hx = st[32]*X + st[33]*Y + st[34]*Z;
    const float hy = st[35]*X + st[36]*Y + st[37]*Z;
    const float hz = st[38]*X + st[39]*Y + st[40]*Z;
    const float sr = st[43];
    const float u = hx / hz, v = hy / hz;
    int ix = (int)floorf(u / sr); ix = min(max(ix, 0), W_-1);
    int iy = (int)floorf(v / sr); iy = min(max(iy, 0), H_-1);
    const int pix = iy * W_ + ix;

    const float4* q4 = (const float4*)(qT + (size_t)pix * C_);
    const float4* f4 = (const float4*)(feat0 + (size_t)n * C_);
    float cost = 0;
#pragma unroll
    for (int i = 0; i < 4; i++) {
        float4 qv = q4[i*64 + lane], fv = f4[i*64 + lane];
        float e;
        e = qv.x - fv.x; cost += e*e;
        e = qv.y - fv.y; cost += e*e;
        e = qv.z - fv.z; cost += e*e;
        e = qv.w - fv.w; cost += e*e;
    }
#pragma unroll
    for (int off = 32; off; off >>= 1) cost += __shfl_xor(cost, off, 64);

    __shared__ float pl[4];
    if (lane == 0) pl[w] = cost;
    __syncthreads();
    if (threadIdx.x == 0) ncostp[blockIdx.x] = pl[0] + pl[1] + pl[2] + pl[3];
}

// ------------------------------------------------------------ accept/reject
__global__ void k_decide(const float* __restrict__ ncostp, float* __restrict__ st) {
    const int lane = threadIdx.x;  // 64 threads
    double s = 0;
#pragma unroll 4
    for (int i = 0; i < NB_/64; i++) s += (double)ncostp[i*64 + lane];
    for (int off = 32; off; off >>= 1) s += __shfl_down(s, off, 64);
    if (lane == 0) {
        float nc = (float)(s / (double)N_);
        float prev = st[13], lam = st[12];
        bool bad = isnan(nc) || (st[72] != 0.f);
        bool worse = nc > prev;
        float lu = lam * (worse ? 10.f : 0.1f);
        lu = fminf(fmaxf(lu, 1e-6f), 100.f);
        st[12] = bad ? lam : lu;
        bool accept = !(worse || bad);
        if (accept) {
            for (int i = 0; i < 9; i++) st[i] = st[14+i];
            for (int i = 0; i < 3; i++) st[9+i] = st[23+i];
            st[13] = nc;
        }
    }
}

__global__ void k_out(const float* __restrict__ st, float* __restrict__ out) {
    int i = threadIdx.x;
    if (i < 12) out[i] = st[i];   // st[0..8]=R, st[9..11]=t -> contiguous
}

extern "C" void kernel_launch(void* const* d_in, const int* in_sizes, int n_in,
                              void* d_out, int out_size, void* d_ws, size_t ws_size,
                              hipStream_t stream) {
    const float* q   = (const float*)d_in[0];
    const float* r   = (const float*)d_in[1];
    const float* p2d = (const float*)d_in[2];
    const float* p3d = (const float*)d_in[3];
    const float* qf  = (const float*)d_in[4];
    const float* rf  = (const float*)d_in[5];
    const float* K1  = (const float*)d_in[6];
    const int*   srp = (const int*)d_in[7];

    float* ws = (float*)d_ws;
    size_t off = 0;
    float* qT    = ws + off; off += (size_t)HW_ * C_;   // 64 MB
    float* gxT   = ws + off; off += (size_t)HW_ * C_;   // 64 MB
    float* gyT   = ws + off; off += (size_t)HW_ * C_;   // 64 MB
    float* feat0 = ws + off; off += (size_t)N_ * C_;    // 32 MB
    float* pts0  = ws + off; off += 3 * N_;
    int*   pix0  = (int*)(ws + off); off += N_;
    float* partial = ws + off; off += (size_t)NCOMP * NB_;
    float* ncostp  = ws + off; off += NB_;
    float* st    = ws + off; off += 128;

    k_setup<<<N_/256, 256, 0, stream>>>(q, r, K1, srp, p3d, p2d, st, pts0, pix0);
    // transpose reference into qT buffer (temporarily), gather feat0, then
    // overwrite qT with the query transpose + fused sobel.
    k_transpose2<false><<<dim3(W_/32, H_/4, C_/16), 256, 0, stream>>>(rf, qT, nullptr, nullptr);
    k_feat0<<<NB_, 256, 0, stream>>>(qT, pix0, feat0);
    k_transpose2<true><<<dim3(W_/32, H_/4, C_/16), 256, 0, stream>>>(qf, qT, gxT, gyT);

    for (int it = 0; it < ITERS; it++) {
        k_passA<<<NB_, 256, 0, stream>>>(qT, gxT, gyT, feat0, pts0, st, partial);
        k_RS<<<1, 1024, 0, stream>>>(partial, st, it);
        k_passB<<<NB_, 256, 0, stream>>>(qT, feat0, pts0, st, ncostp);
        k_decide<<<1, 64, 0, stream>>>(ncostp, st);
    }
    k_out<<<1, 64, 0, stream>>>(st, (float*)d_out);
}